// Round 1
// baseline (118.808 us; speedup 1.0000x reference)
//
#include <hip/hip_runtime.h>

#define CAM_FL 540.0f
#define CAM_W  640
#define CAM_H  480
#define RADIUS 2

// One thread per particle. blockIdx.y = batch index so camera params are
// block-uniform (compiler can scalarize). Scatter with global float atomics.
__global__ __launch_bounds__(256) void particle_project_kernel(
    const float* __restrict__ locs,        // [B, N, 3]
    const float* __restrict__ camera_pose, // [B, 3]
    const float* __restrict__ camera_rot,  // [B, 4]
    const float* __restrict__ depth,       // [B, H, W]
    float* __restrict__ out,               // [B, H, W]
    int N)
{
#pragma clang fp contract(off)
    const int b = blockIdx.y;
    const int n = blockIdx.x * blockDim.x + threadIdx.x;
    if (n >= N) return;

    // --- camera params (uniform within block) ---
    const float qx_raw = camera_rot[b * 4 + 0];
    const float qy_raw = camera_rot[b * 4 + 1];
    const float qz_raw = camera_rot[b * 4 + 2];
    const float qw_raw = camera_rot[b * 4 + 3];
    // norm: sequential sum order to match numpy float32
    const float norm2 = ((qx_raw * qx_raw + qy_raw * qy_raw) + qz_raw * qz_raw) + qw_raw * qw_raw;
    const float s = sqrtf(norm2);
    // normalize then conjugate (negate vector part), as in reference
    const float qx = -(qx_raw / s);
    const float qy = -(qy_raw / s);
    const float qz = -(qz_raw / s);
    const float qw =  (qw_raw / s);

    const float qx2 = qx * qx, qy2 = qy * qy, qz2 = qz * qz;
    const float qxqy = qx * qy, qxqz = qx * qz, qxqw = qx * qw;
    const float qyqz = qy * qz, qyqw = qy * qw, qzqw = qz * qw;
    // R rows as in _rot_from_quat (R[i][j]); p' = p . R  (p'_j = sum_i p_i R_ij)
    const float r00 = (1.0f - 2.0f * qy2) - 2.0f * qz2;
    const float r10 = 2.0f * qxqy - 2.0f * qzqw;
    const float r20 = 2.0f * qxqz + 2.0f * qyqw;
    const float r01 = 2.0f * qxqy + 2.0f * qzqw;
    const float r11 = (1.0f - 2.0f * qx2) - 2.0f * qz2;
    const float r21 = 2.0f * qyqz - 2.0f * qxqw;
    const float r02 = 2.0f * qxqz - 2.0f * qyqw;
    const float r12 = 2.0f * qyqz + 2.0f * qxqw;
    const float r22 = (1.0f - 2.0f * qx2) - 2.0f * qy2;

    const float cpx = camera_pose[b * 3 + 0];
    const float cpy = camera_pose[b * 3 + 1];
    const float cpz = camera_pose[b * 3 + 2];

    // --- particle ---
    const float p0 = locs[(size_t)(b * N + n) * 3 + 0] - cpx;
    const float p1 = locs[(size_t)(b * N + n) * 3 + 1] - cpy;
    const float p2 = locs[(size_t)(b * N + n) * 3 + 2] - cpz;

    // p' = p . R, association order matches reference ((a+b)+c)
    const float x = (p0 * r00 + p1 * r10) + p2 * r20;
    const float y = (p0 * r01 + p1 * r11) + p2 * r21;
    const float z = (p0 * r02 + p1 * r12) + p2 * r22;

    // valid requires z > 0 (reference zeroes all weights otherwise)
    if (!(z > 0.0f)) return;

    const float px = (x / z) * CAM_FL + (float)CAM_W * 0.5f;
    const float py = (y / z) * CAM_FL + (float)CAM_H * 0.5f;

    // frustum cull in float domain BEFORE int conversion (avoids f->i overflow
    // for Cauchy-tail projections). Stamp intersects image iff
    // floor(px) in [-RADIUS, W-1+RADIUS] and floor(py) in [-RADIUS, H-1+RADIUS].
    if (!(px >= -(float)RADIUS && px < (float)(CAM_W + RADIUS) &&
          py >= -(float)RADIUS && py < (float)(CAM_H + RADIUS)))
        return;

    const int jx0 = (int)floorf(px);
    const int iy0 = (int)floorf(py);

    const float* depth_b = depth + (size_t)b * CAM_H * CAM_W;
    float* out_b = out + (size_t)b * CAM_H * CAM_W;

#pragma unroll
    for (int i = 0; i < 2 * RADIUS + 1; ++i) {
        const int iy = iy0 + i - RADIUS;
        if ((unsigned)iy >= (unsigned)CAM_H) continue;
        const float dyf = (float)iy - py;
        const float dy2 = dyf * dyf;
#pragma unroll
        for (int j = 0; j < 2 * RADIUS + 1; ++j) {
            const int jx = jx0 + j - RADIUS;
            if ((unsigned)jx >= (unsigned)CAM_W) continue;
            const float dxf = (float)jx - px;
            const size_t pix = (size_t)iy * CAM_W + jx;
            const float d = depth_b[pix];
            if (z <= d) {
                // w = exp(-(dy^2 + dx^2) / 2), FILTER_SCALE = 1
                const float w = expf(-(dy2 + dxf * dxf) * 0.5f);
                atomicAdd(&out_b[pix], w);
            }
        }
    }
}

extern "C" void kernel_launch(void* const* d_in, const int* in_sizes, int n_in,
                              void* d_out, int out_size, void* d_ws, size_t ws_size,
                              hipStream_t stream) {
    const float* locs        = (const float*)d_in[0];
    const float* camera_pose = (const float*)d_in[1];
    const float* camera_rot  = (const float*)d_in[2];
    const float* depth_mask  = (const float*)d_in[3];
    float* out = (float*)d_out;

    const int B = in_sizes[1] / 3;             // camera_pose is [B,3]
    const int N = in_sizes[0] / (3 * B);       // locs is [B,N,3]

    // harness poisons d_out with 0xAA before every timed launch
    hipMemsetAsync(d_out, 0, (size_t)out_size * sizeof(float), stream);

    dim3 block(256, 1, 1);
    dim3 grid((N + 255) / 256, B, 1);
    particle_project_kernel<<<grid, block, 0, stream>>>(
        locs, camera_pose, camera_rot, depth_mask, out, N);
}